// Round 15
// baseline (527.260 us; speedup 1.0000x reference)
//
#include <hip/hip_runtime.h>

#define B_ 256
#define E_ 1024
#define H_ 1024
#define F_ 2048
#define L_ 196
#define A_ 512
#define ML (B_ * L_)   // 50176

typedef __attribute__((ext_vector_type(8))) short short8;
typedef __attribute__((ext_vector_type(4))) float f32x4;

__device__ __forceinline__ unsigned short f2bf(float x) {
  unsigned u = __float_as_uint(x);
  unsigned r = (u + 0x7FFFu + ((u >> 16) & 1u)) >> 16;   // RNE
  return (unsigned short)r;
}
__device__ __forceinline__ float fast_tanh(float x) {
  x = fminf(fmaxf(x, -15.f), 15.f);
  float e = __expf(2.f * x);
  return (e - 1.f) / (e + 1.f);
}
__device__ __forceinline__ float sigmoidf_(float x) {
  return 1.f / (1.f + __expf(-x));
}

#define GLOAD_LDS(gptr, lptr) \
  __builtin_amdgcn_global_load_lds( \
      (const __attribute__((address_space(1))) void*)(gptr), \
      (__attribute__((address_space(3))) void*)(lptr), 16, 0, 0)

#define SBAR() asm volatile("s_barrier" ::: "memory")
#define LGKM0() asm volatile("s_waitcnt lgkmcnt(0)" ::: "memory")
#define VMCNT(N) asm volatile("s_waitcnt vmcnt(" #N ")" ::: "memory")
#define SCHEDB() __builtin_amdgcn_sched_barrier(0)

// ---------------- merged weight + xh casts ----------------
// flat ranges: [0,1048576) Wa ; [1048576,1572864) Wha ; [1572864,18350080) Wg ;
// [18350080,18874368) xt|h -> AgB cols 0..2047.  grid = 18874368/2048 = 9216 blocks.
__global__ void cast_wx_k(const float* __restrict__ Wa, const float* __restrict__ Wha,
                          const float* __restrict__ Wi, const float* __restrict__ Wh,
                          const float* __restrict__ Wz, const float* __restrict__ xt,
                          const float* __restrict__ h,
                          unsigned short* __restrict__ WaB, unsigned short* __restrict__ WhaB,
                          unsigned short* __restrict__ WgB, unsigned short* __restrict__ AgB) {
  size_t i = ((size_t)blockIdx.x * 256 + threadIdx.x) * 8;
  const float* src;
  unsigned short* dst;
  if (i < 1048576) { src = Wa + i; dst = WaB + i; }
  else if (i < 1572864) { src = Wha + (i - 1048576); dst = WhaB + (i - 1048576); }
  else if (i < 18350080) {
    size_t off = i - 1572864;
    int row = (int)(off >> 12), col = (int)(off & 4095);
    if (col < 1024)       src = Wi + (size_t)row * 1024 + col;
    else if (col < 2048)  src = Wh + (size_t)row * 1024 + (col - 1024);
    else                  src = Wz + (size_t)row * 2048 + (col - 2048);
    dst = WgB + off;
  } else {
    size_t off = i - 18350080;
    int row = (int)(off >> 11), col = (int)(off & 2047);
    src = (col < 1024) ? (xt + (size_t)row * 1024 + col) : (h + (size_t)row * 1024 + (col - 1024));
    dst = AgB + (size_t)row * 4096 + col;
  }
  float4 a = *reinterpret_cast<const float4*>(src);
  float4 b = *reinterpret_cast<const float4*>(src + 4);
  short8 o;
  o[0] = (short)f2bf(a.x); o[1] = (short)f2bf(a.y); o[2] = (short)f2bf(a.z); o[3] = (short)f2bf(a.w);
  o[4] = (short)f2bf(b.x); o[5] = (short)f2bf(b.y); o[6] = (short)f2bf(b.z); o[7] = (short)f2bf(b.w);
  *reinterpret_cast<short8*>(dst) = o;
}

// ---------------- hlin = h @ Wha^T + bha via MFMA: M=256,N=512,K=1024 ----------------
__global__ __launch_bounds__(256, 2)
void hlin_gemm_k(const unsigned short* __restrict__ AgB, const unsigned short* __restrict__ WhaB,
                 const float* __restrict__ bha, float* __restrict__ hlin) {
  __shared__ unsigned short As[2][64 * 64];
  __shared__ unsigned short Bs[2][128 * 64];
  const int tid = threadIdx.x;
  const int lane = tid & 63, wid = tid >> 6;
  const int wm = wid >> 1, wn = wid & 1;
  const int m0 = blockIdx.y * 64;
  const int n0 = blockIdx.x * 128;
  const int g16 = lane >> 4, l16 = lane & 15;
  const int l7 = l16 & 7;
  f32x4 acc[2][4] = {};

#define STAGE_HL(BUF, KK)                                                                      \
  {                                                                                            \
    _Pragma("unroll")                                                                          \
    for (int it = 0; it < 2; ++it) {                                                           \
      int idx = it * 256 + tid;                                                                \
      int row = idx >> 3;                                                                      \
      int kc = (idx & 7) ^ (row & 7);                                                          \
      GLOAD_LDS(AgB + (size_t)(m0 + row) * 4096 + 1024 + (KK) + kc * 8, &As[BUF][idx * 8]);    \
    }                                                                                          \
    _Pragma("unroll")                                                                          \
    for (int it = 0; it < 4; ++it) {                                                           \
      int idx = it * 256 + tid;                                                                \
      int row = idx >> 3;                                                                      \
      int kc = (idx & 7) ^ (row & 7);                                                          \
      GLOAD_LDS(WhaB + (size_t)(n0 + row) * 1024 + (KK) + kc * 8, &Bs[BUF][idx * 8]);          \
    }                                                                                          \
  }

  STAGE_HL(0, 0);
  STAGE_HL(1, 64);
  VMCNT(6);
  SBAR();
  int cur = 0;
  for (int k0 = 0; k0 < 1024; k0 += 64) {
    #pragma unroll
    for (int ks = 0; ks < 2; ++ks) {
      const int ko = ((ks * 4 + g16) ^ l7) << 3;
      short8 af[2], bfr[4];
      #pragma unroll
      for (int mi = 0; mi < 2; ++mi)
        af[mi] = *reinterpret_cast<const short8*>(&As[cur][(wm * 32 + mi * 16 + l16) * 64 + ko]);
      #pragma unroll
      for (int ni = 0; ni < 4; ++ni)
        bfr[ni] = *reinterpret_cast<const short8*>(&Bs[cur][(wn * 64 + ni * 16 + l16) * 64 + ko]);
      #pragma unroll
      for (int mi = 0; mi < 2; ++mi)
        #pragma unroll
        for (int ni = 0; ni < 4; ++ni)
          acc[mi][ni] = __builtin_amdgcn_mfma_f32_16x16x32_bf16(af[mi], bfr[ni], acc[mi][ni], 0, 0, 0);
    }
    LGKM0();
    SBAR();
    if (k0 + 128 < 1024) {
      STAGE_HL(cur, k0 + 128);
      VMCNT(6);
    } else {
      VMCNT(0);
    }
    SBAR();
    cur ^= 1;
  }
#undef STAGE_HL

  #pragma unroll
  for (int ni = 0; ni < 4; ++ni) {
    int col = n0 + wn * 64 + ni * 16 + l16;
    float bv = bha[col];
    #pragma unroll
    for (int mi = 0; mi < 2; ++mi)
      #pragma unroll
      for (int j = 0; j < 4; ++j) {
        int m = m0 + wm * 32 + mi * 16 + g16 * 4 + j;
        hlin[(size_t)m * A_ + col] = acc[mi][ni][j] + bv;
      }
  }
}

// ---------------- fused cast+score GEMM v6d: BM=64, BN=256, 3 blocks/CU ----------------
// Race fix vs rounds 12-14: every vmcnt separates load GROUPS -- an asm volatile wait
// sits between GLDB and LOADA so the compiler cannot interleave their issue order,
// making the retirement counts exact: vmcnt(8) frees the A-reg set, vmcnt(4) frees B.
// scores2[m][2]: slot = n0>>8.
__global__ __launch_bounds__(256, 3)
void score_fuse_k(const float* __restrict__ att, const unsigned short* __restrict__ WaB,
                  const float* __restrict__ hlin, const float* __restrict__ ba,
                  const float* __restrict__ Wo, float* __restrict__ scores2) {
  __shared__ unsigned short As[2][64 * 64];     // 16 KB
  __shared__ unsigned short Bs[256 * 64];       // 32 KB single buffer
  const int tid = threadIdx.x;
  const int lane = tid & 63, wn = tid >> 6;     // 4 waves
  // XCD swizzle: 1568 blocks % 8 == 0; N-fastest so the M-pair shares L2.
  const int logical = (blockIdx.x & 7) * 196 + (blockIdx.x >> 3);
  const int m0 = (logical >> 1) * 64;
  const int n0 = (logical & 1) * 256;
  const int g16 = lane >> 4, l16 = lane & 15;
  const int l7 = l16 & 7;
  f32x4 acc[4][4] = {};
  float4 Ra[4], Rb[4];

#define LOADA(REG, KK)                                                                   \
  {                                                                                      \
    _Pragma("unroll")                                                                    \
    for (int it = 0; it < 4; ++it) {                                                     \
      int idx = it * 256 + tid;                                                          \
      int row = idx >> 4, kf = idx & 15;                                                 \
      REG[it] = *reinterpret_cast<const float4*>(att + (size_t)(m0 + row) * F_ + (KK) + kf * 4); \
    }                                                                                    \
  }
#define GLDB(KK)                                                                         \
  {                                                                                      \
    _Pragma("unroll")                                                                    \
    for (int it = 0; it < 8; ++it) {                                                     \
      int idx = it * 256 + tid;                                                          \
      int row = idx >> 3;                                                                \
      int kc = (idx & 7) ^ (row & 7);                                                    \
      GLOAD_LDS(WaB + (size_t)(n0 + row) * F_ + (KK) + kc * 8, &Bs[idx * 8]);            \
    }                                                                                    \
  }
#define WRITEA(BUF, REG)                                                                 \
  {                                                                                      \
    _Pragma("unroll")                                                                    \
    for (int it = 0; it < 4; ++it) {                                                     \
      int idx = it * 256 + tid;                                                          \
      int row = idx >> 4, kf = idx & 15;                                                 \
      float4 v = REG[it];                                                                \
      unsigned lo, hi;                                                                   \
      asm("v_cvt_pk_bf16_f32 %0, %1, %2" : "=v"(lo) : "v"(v.x), "v"(v.y));               \
      asm("v_cvt_pk_bf16_f32 %0, %1, %2" : "=v"(hi) : "v"(v.z), "v"(v.w));               \
      uint2 q; q.x = lo; q.y = hi;                                                       \
      int el = row * 64 + (((kf >> 1) ^ (row & 7)) << 3) + ((kf & 1) << 2);              \
      *reinterpret_cast<uint2*>(&As[BUF][el]) = q;                                       \
    }                                                                                    \
  }
#define COMPUTE(BUF)                                                                     \
  {                                                                                      \
    _Pragma("unroll")                                                                    \
    for (int ks = 0; ks < 2; ++ks) {                                                     \
      const int ko = ((ks * 4 + g16) ^ l7) << 3;                                         \
      short8 af[4], bfr[4];                                                              \
      _Pragma("unroll")                                                                  \
      for (int mi = 0; mi < 4; ++mi)                                                     \
        af[mi] = *reinterpret_cast<const short8*>(&As[BUF][(mi * 16 + l16) * 64 + ko]);  \
      _Pragma("unroll")                                                                  \
      for (int ni = 0; ni < 4; ++ni)                                                     \
        bfr[ni] = *reinterpret_cast<const short8*>(&Bs[(wn * 64 + ni * 16 + l16) * 64 + ko]); \
      _Pragma("unroll")                                                                  \
      for (int mi = 0; mi < 4; ++mi)                                                     \
        _Pragma("unroll")                                                                \
        for (int ni = 0; ni < 4; ++ni)                                                   \
          acc[mi][ni] = __builtin_amdgcn_mfma_f32_16x16x32_bf16(af[mi], bfr[ni], acc[mi][ni], 0, 0, 0); \
    }                                                                                    \
  }

  // prologue: A(0)+B(0) fully staged; Rb=A(1) in flight (issued AFTER vmcnt(0))
  LOADA(Ra, 0);
  GLDB(0);
  VMCNT(0);                                           // A(0) + B(0) all done
  WRITEA(0, Ra);
  LOADA(Rb, 64);                                      // A(1): 4 loads outstanding
  LGKM0();
  SBAR();

  for (int p = 0; p < 16; ++p) {
    const int t = 2 * p;
    SCHEDB();
    COMPUTE(0);                                       // A(t), B(t)
    LGKM0();                                          // all ds_reads complete
    SBAR();                                           // ...before anyone refills Bs
    GLDB((t + 1) * 64);                               // B(t+1): outstanding Rb4+B8=12
    VMCNT(8);                                         // Rb (strictly oldest) retired
    WRITEA(1, Rb);                                    // As[1] <- A(t+1)
    if (t + 2 < 32) {
      LOADA(Ra, (t + 2) * 64);                        // A(t+2): outstanding B8+Ra4
      VMCNT(4);                                       // B(t+1) (older group) done; Ra flying
    } else {
      VMCNT(0);
    }
    LGKM0();
    SBAR();

    SCHEDB();
    COMPUTE(1);                                       // A(t+1), B(t+1)
    LGKM0();
    SBAR();
    if (t + 2 < 32) {
      GLDB((t + 2) * 64);                             // outstanding Ra4+B8=12
      VMCNT(8);                                       // Ra retired
      WRITEA(0, Ra);                                  // As[0] <- A(t+2)
      if (t + 3 < 32) {
        LOADA(Rb, (t + 3) * 64);
        VMCNT(4);                                     // B(t+2) done; Rb flying
      } else {
        VMCNT(0);
      }
      LGKM0();
      SBAR();
    }
  }
#undef LOADA
#undef GLDB
#undef WRITEA
#undef COMPUTE

  // epilogue: per-wave tanh+Wo partial over its 64 cols; cross-wave reduce (red overlays As)
  __syncthreads();
  float* red = (float*)&As[0][0];                     // 4*64 floats
  float wo_v[4], ba_v[4];
  int a_v[4];
  #pragma unroll
  for (int ni = 0; ni < 4; ++ni) {
    int a = n0 + wn * 64 + ni * 16 + l16;
    a_v[ni] = a; wo_v[ni] = Wo[a]; ba_v[ni] = ba[a];
  }
  #pragma unroll
  for (int mi = 0; mi < 4; ++mi) {
    float rs[4];
    #pragma unroll
    for (int j = 0; j < 4; ++j) {
      int m = m0 + mi * 16 + g16 * 4 + j;
      int b = m / L_;
      const float* hb = hlin + (size_t)b * A_;
      float s = 0.f;
      #pragma unroll
      for (int ni = 0; ni < 4; ++ni) {
        float v = acc[mi][ni][j] + ba_v[ni] + hb[a_v[ni]];
        s += fast_tanh(v) * wo_v[ni];
      }
      rs[j] = s;
    }
    #pragma unroll
    for (int off = 1; off < 16; off <<= 1) {
      #pragma unroll
      for (int j = 0; j < 4; ++j) rs[j] += __shfl_xor(rs[j], off);
    }
    if (l16 == 0) {
      #pragma unroll
      for (int j = 0; j < 4; ++j)
        red[wn * 64 + mi * 16 + g16 * 4 + j] = rs[j];
    }
  }
  __syncthreads();
  if (tid < 64) {
    float s = red[tid] + red[64 + tid] + red[128 + tid] + red[192 + tid];
    scores2[(size_t)(m0 + tid) * 2 + (n0 >> 8)] = s;
  }
}

// ---------------- fused softmax + z (f32 att) ----------------
__global__ __launch_bounds__(256)
void z_sm_f32_k(const float* __restrict__ att, const float* __restrict__ scores2,
                unsigned short* __restrict__ AgB) {
  __shared__ float sm[L_];
  const int b = blockIdx.y;
  const int tid = threadIdx.x;
  if (tid < L_) {
    const float* p = scores2 + ((size_t)b * L_ + tid) * 2;
    sm[tid] = p[0] + p[1];
  }
  __syncthreads();
  float mx = -1e30f;
  for (int l = 0; l < L_; ++l) mx = fmaxf(mx, sm[l]);
  float s = 0.f;
  for (int l = 0; l < L_; ++l) s += __expf(sm[l] - mx);
  const float inv = 1.f / s;
  __syncthreads();
  if (tid < L_) sm[tid] = __expf(sm[tid] - mx) * inv;
  __syncthreads();
  const int f0 = blockIdx.x * 1024 + tid * 4;
  const float* base = att + (size_t)b * L_ * F_ + f0;
  float a0 = 0.f, a1 = 0.f, a2 = 0.f, a3 = 0.f;
  #pragma unroll 4
  for (int l = 0; l < L_; ++l) {
    float wl = sm[l];
    float4 a = *reinterpret_cast<const float4*>(base + (size_t)l * F_);
    a0 += wl * a.x; a1 += wl * a.y; a2 += wl * a.z; a3 += wl * a.w;
  }
  ushort4 o;
  o.x = f2bf(a0); o.y = f2bf(a1); o.z = f2bf(a2); o.w = f2bf(a3);
  *reinterpret_cast<ushort4*>(AgB + (size_t)b * 4096 + 2048 + f0) = o;
}

// ---------------- gates GEMM: M=256,N=4096,K=4096. BM=64,BN=64, grid(64,4) ----------------
__global__ __launch_bounds__(256, 4)
void gates_gemm_k(const unsigned short* __restrict__ AgB, const unsigned short* __restrict__ WgB,
                  const float* __restrict__ bi, const float* __restrict__ bh,
                  const float* __restrict__ bz, float* __restrict__ sums) {
  __shared__ unsigned short As[2][64 * 64];
  __shared__ unsigned short Bs[2][64 * 64];
  const int tid = threadIdx.x;
  const int lane = tid & 63, wid = tid >> 6;
  const int wm = wid >> 1, wn = wid & 1;
  const int m0 = blockIdx.y * 64;
  const int n0 = blockIdx.x * 64;
  const int g16 = lane >> 4, l16 = lane & 15;
  const int l7 = l16 & 7;
  f32x4 acc[2][2] = {};

#define STAGE_GG(BUF, KK)                                                               \
  {                                                                                     \
    _Pragma("unroll")                                                                   \
    for (int it = 0; it < 2; ++it) {                                                    \
      int idx = it * 256 + tid;                                                         \
      int row = idx >> 3;                                                               \
      int kc = (idx & 7) ^ (row & 7);                                                   \
      GLOAD_LDS(AgB + (size_t)(m0 + row) * 4096 + (KK) + kc * 8, &As[BUF][idx * 8]);    \
      GLOAD_LDS(WgB + (size_t)(n0 + row) * 4096 + (KK) + kc * 8, &Bs[BUF][idx * 8]);    \
    }                                                                                   \
  }

  STAGE_GG(0, 0);
  STAGE_GG(1, 64);
  VMCNT(4);
  SBAR();
  int cur = 0;
  for (int k0 = 0; k0 < 4096; k0 += 64) {
    #pragma unroll
    for (int ks = 0; ks < 2; ++ks) {
      const int ko = ((ks * 4 + g16) ^ l7) << 3;
      short8 af[2], bfr[2];
      #pragma unroll
      for (int mi = 0; mi < 2; ++mi)
        af[mi] = *reinterpret_cast<const short8*>(&As[cur][(wm * 32 + mi * 16 + l16) * 64 + ko]);
      #pragma unroll
      for (int ni = 0; ni < 2; ++ni)
        bfr[ni] = *reinterpret_cast<const short8*>(&Bs[cur][(wn * 32 + ni * 16 + l16) * 64 + ko]);
      #pragma unroll
      for (int mi = 0; mi < 2; ++mi)
        #pragma unroll
        for (int ni = 0; ni < 2; ++ni)
          acc[mi][ni] = __builtin_amdgcn_mfma_f32_16x16x32_bf16(af[mi], bfr[ni], acc[mi][ni], 0, 0, 0);
    }
    LGKM0();
    SBAR();
    if (k0 + 128 < 4096) {
      STAGE_GG(cur, k0 + 128);
      VMCNT(4);
    } else {
      VMCNT(0);
    }
    SBAR();
    cur ^= 1;
  }
#undef STAGE_GG

  #pragma unroll
  for (int ni = 0; ni < 2; ++ni) {
    int col = n0 + wn * 32 + ni * 16 + l16;
    float bsum = bi[col] + bh[col] + bz[col];
    #pragma unroll
    for (int mi = 0; mi < 2; ++mi)
      #pragma unroll
      for (int j = 0; j < 4; ++j) {
        int m = m0 + wm * 32 + mi * 16 + g16 * 4 + j;
        sums[(size_t)m * 4096 + col] = acc[mi][ni][j] + bsum;
      }
  }
}

// ---------------- gates + zoneout elementwise ----------------
__global__ void final_k(const float* __restrict__ sums, const float* __restrict__ h,
                        const float* __restrict__ c, float* __restrict__ out) {
  int i = blockIdx.x * 256 + threadIdx.x;   // 0 .. B_*H_-1
  int b = i >> 10, hh = i & 1023;
  const float* srow = sums + (size_t)b * 4096;
  float ig = sigmoidf_(srow[hh]);
  float fg = sigmoidf_(srow[1024 + hh]);
  float og = sigmoidf_(srow[2048 + hh]);
  float g  = fast_tanh(srow[3072 + hh]);
  float cv = c[i], hv = h[i];
  float nc = 0.5f * cv + 0.5f * (fg * cv + ig * g);
  float nh = 0.5f * hv + 0.5f * (og * fast_tanh(nc));
  out[i] = nh;
  out[B_ * H_ + i] = nh;
  out[2 * B_ * H_ + i] = nc;
}

extern "C" void kernel_launch(void* const* d_in, const int* in_sizes, int n_in,
                              void* d_out, int out_size, void* d_ws, size_t ws_size,
                              hipStream_t stream) {
  const float* xt  = (const float*)d_in[0];
  const float* att = (const float*)d_in[1];
  const float* h   = (const float*)d_in[2];
  const float* c   = (const float*)d_in[3];
  const float* Wi  = (const float*)d_in[4];
  const float* bi  = (const float*)d_in[5];
  const float* Wh  = (const float*)d_in[6];
  const float* bh  = (const float*)d_in[7];
  const float* Wz  = (const float*)d_in[8];
  const float* bz  = (const float*)d_in[9];
  const float* Wa  = (const float*)d_in[10];
  const float* ba  = (const float*)d_in[11];
  const float* Wha = (const float*)d_in[12];
  const float* bha = (const float*)d_in[13];
  const float* Wo  = (const float*)d_in[14];
  // bo (d_in[15]) is a constant shift under softmax -> dropped.

  char* ws = (char*)d_ws;
  const size_t MB = (size_t)1 << 20;
  unsigned short* WaB  = (unsigned short*)(ws);                // 2 MB
  unsigned short* WhaB = (unsigned short*)(ws + 2 * MB);       // 1 MB
  unsigned short* WgB  = (unsigned short*)(ws + 3 * MB);       // 32 MB
  unsigned short* AgB  = (unsigned short*)(ws + 35 * MB);      // 2 MB
  float* hlin    = (float*)(ws + 37 * MB);                     // 0.5 MB
  float* scores2 = (float*)(ws + 38 * MB);                     // 0.4 MB
  float* sums    = (float*)(ws + 40 * MB);                     // 4 MB
  float* out = (float*)d_out;

  cast_wx_k<<<9216, 256, 0, stream>>>(Wa, Wha, Wi, Wh, Wz, xt, h, WaB, WhaB, WgB, AgB);
  hlin_gemm_k<<<dim3(4, 4), 256, 0, stream>>>(AgB, WhaB, bha, hlin);
  score_fuse_k<<<(ML / 64) * 2, 256, 0, stream>>>(att, WaB, hlin, ba, Wo, scores2);
  z_sm_f32_k<<<dim3(2, B_), 256, 0, stream>>>(att, scores2, AgB);
  gates_gemm_k<<<dim3(64, 4), 256, 0, stream>>>(AgB, WgB, bi, bh, bz, sums);
  final_k<<<B_ * H_ / 256, 256, 0, stream>>>(sums, h, c, out);
}

// Round 16
// 391.186 us; speedup vs baseline: 1.3478x; 1.3478x over previous
//
#include <hip/hip_runtime.h>

#define B_ 256
#define E_ 1024
#define H_ 1024
#define F_ 2048
#define L_ 196
#define A_ 512
#define ML (B_ * L_)   // 50176

typedef __attribute__((ext_vector_type(8))) short short8;
typedef __attribute__((ext_vector_type(4))) float f32x4;

__device__ __forceinline__ unsigned short f2bf(float x) {
  unsigned u = __float_as_uint(x);
  unsigned r = (u + 0x7FFFu + ((u >> 16) & 1u)) >> 16;   // RNE
  return (unsigned short)r;
}
__device__ __forceinline__ float fast_tanh(float x) {
  x = fminf(fmaxf(x, -15.f), 15.f);
  float e = __expf(2.f * x);
  return (e - 1.f) / (e + 1.f);
}
__device__ __forceinline__ float sigmoidf_(float x) {
  return 1.f / (1.f + __expf(-x));
}

#define GLOAD_LDS(gptr, lptr) \
  __builtin_amdgcn_global_load_lds( \
      (const __attribute__((address_space(1))) void*)(gptr), \
      (__attribute__((address_space(3))) void*)(lptr), 16, 0, 0)

#define SBAR() asm volatile("s_barrier" ::: "memory")
#define LGKM0() asm volatile("s_waitcnt lgkmcnt(0)" ::: "memory")
#define VMCNT(N) asm volatile("s_waitcnt vmcnt(" #N ")" ::: "memory")

// ---------------- merged weight + xh casts ----------------
// flat ranges: [0,1048576) Wa ; [1048576,1572864) Wha ; [1572864,18350080) Wg ;
// [18350080,18874368) xt|h -> AgB cols 0..2047.  grid = 18874368/2048 = 9216 blocks.
__global__ void cast_wx_k(const float* __restrict__ Wa, const float* __restrict__ Wha,
                          const float* __restrict__ Wi, const float* __restrict__ Wh,
                          const float* __restrict__ Wz, const float* __restrict__ xt,
                          const float* __restrict__ h,
                          unsigned short* __restrict__ WaB, unsigned short* __restrict__ WhaB,
                          unsigned short* __restrict__ WgB, unsigned short* __restrict__ AgB) {
  size_t i = ((size_t)blockIdx.x * 256 + threadIdx.x) * 8;
  const float* src;
  unsigned short* dst;
  if (i < 1048576) { src = Wa + i; dst = WaB + i; }
  else if (i < 1572864) { src = Wha + (i - 1048576); dst = WhaB + (i - 1048576); }
  else if (i < 18350080) {
    size_t off = i - 1572864;
    int row = (int)(off >> 12), col = (int)(off & 4095);
    if (col < 1024)       src = Wi + (size_t)row * 1024 + col;
    else if (col < 2048)  src = Wh + (size_t)row * 1024 + (col - 1024);
    else                  src = Wz + (size_t)row * 2048 + (col - 2048);
    dst = WgB + off;
  } else {
    size_t off = i - 18350080;
    int row = (int)(off >> 11), col = (int)(off & 2047);
    src = (col < 1024) ? (xt + (size_t)row * 1024 + col) : (h + (size_t)row * 1024 + (col - 1024));
    dst = AgB + (size_t)row * 4096 + col;
  }
  float4 a = *reinterpret_cast<const float4*>(src);
  float4 b = *reinterpret_cast<const float4*>(src + 4);
  short8 o;
  o[0] = (short)f2bf(a.x); o[1] = (short)f2bf(a.y); o[2] = (short)f2bf(a.z); o[3] = (short)f2bf(a.w);
  o[4] = (short)f2bf(b.x); o[5] = (short)f2bf(b.y); o[6] = (short)f2bf(b.z); o[7] = (short)f2bf(b.w);
  *reinterpret_cast<short8*>(dst) = o;
}

// ---------------- hlin = h @ Wha^T + bha via MFMA: M=256,N=512,K=1024 ----------------
__global__ __launch_bounds__(256, 2)
void hlin_gemm_k(const unsigned short* __restrict__ AgB, const unsigned short* __restrict__ WhaB,
                 const float* __restrict__ bha, float* __restrict__ hlin) {
  __shared__ unsigned short As[2][64 * 64];
  __shared__ unsigned short Bs[2][128 * 64];
  const int tid = threadIdx.x;
  const int lane = tid & 63, wid = tid >> 6;
  const int wm = wid >> 1, wn = wid & 1;
  const int m0 = blockIdx.y * 64;
  const int n0 = blockIdx.x * 128;
  const int g16 = lane >> 4, l16 = lane & 15;
  const int l7 = l16 & 7;
  f32x4 acc[2][4] = {};

#define STAGE_HL(BUF, KK)                                                                      \
  {                                                                                            \
    _Pragma("unroll")                                                                          \
    for (int it = 0; it < 2; ++it) {                                                           \
      int idx = it * 256 + tid;                                                                \
      int row = idx >> 3;                                                                      \
      int kc = (idx & 7) ^ (row & 7);                                                          \
      GLOAD_LDS(AgB + (size_t)(m0 + row) * 4096 + 1024 + (KK) + kc * 8, &As[BUF][idx * 8]);    \
    }                                                                                          \
    _Pragma("unroll")                                                                          \
    for (int it = 0; it < 4; ++it) {                                                           \
      int idx = it * 256 + tid;                                                                \
      int row = idx >> 3;                                                                      \
      int kc = (idx & 7) ^ (row & 7);                                                          \
      GLOAD_LDS(WhaB + (size_t)(n0 + row) * 1024 + (KK) + kc * 8, &Bs[BUF][idx * 8]);          \
    }                                                                                          \
  }

  STAGE_HL(0, 0);
  STAGE_HL(1, 64);
  VMCNT(6);
  SBAR();
  int cur = 0;
  for (int k0 = 0; k0 < 1024; k0 += 64) {
    #pragma unroll
    for (int ks = 0; ks < 2; ++ks) {
      const int ko = ((ks * 4 + g16) ^ l7) << 3;
      short8 af[2], bfr[4];
      #pragma unroll
      for (int mi = 0; mi < 2; ++mi)
        af[mi] = *reinterpret_cast<const short8*>(&As[cur][(wm * 32 + mi * 16 + l16) * 64 + ko]);
      #pragma unroll
      for (int ni = 0; ni < 4; ++ni)
        bfr[ni] = *reinterpret_cast<const short8*>(&Bs[cur][(wn * 64 + ni * 16 + l16) * 64 + ko]);
      #pragma unroll
      for (int mi = 0; mi < 2; ++mi)
        #pragma unroll
        for (int ni = 0; ni < 4; ++ni)
          acc[mi][ni] = __builtin_amdgcn_mfma_f32_16x16x32_bf16(af[mi], bfr[ni], acc[mi][ni], 0, 0, 0);
    }
    LGKM0();
    SBAR();
    if (k0 + 128 < 1024) {
      STAGE_HL(cur, k0 + 128);
      VMCNT(6);
    } else {
      VMCNT(0);
    }
    SBAR();
    cur ^= 1;
  }
#undef STAGE_HL

  #pragma unroll
  for (int ni = 0; ni < 4; ++ni) {
    int col = n0 + wn * 64 + ni * 16 + l16;
    float bv = bha[col];
    #pragma unroll
    for (int mi = 0; mi < 2; ++mi)
      #pragma unroll
      for (int j = 0; j < 4; ++j) {
        int m = m0 + wm * 32 + mi * 16 + g16 * 4 + j;
        hlin[(size_t)m * A_ + col] = acc[mi][ni][j] + bv;
      }
  }
}

// ---------------- fused cast+score GEMM v8: BM=64, BN=256, FULL double-buffer ----------------
// Round-8's proven schedule (tile-granular vmcnt(12), LOADA+GLDB issued together per tile
// -> count is interleave-insensitive), reshaped to BN=256 to halve A-traffic.
// LDS = As dbuf 16KB + Bs dbuf 64KB = 80KB -> 2 blocks/CU (same occupancy as round 8).
// 4 waves all in N: wave wn owns cols [n0+wn*64, +64). scores2[m][2]: slot = n0>>8.
__global__ __launch_bounds__(256, 2)
void score_fuse_k(const float* __restrict__ att, const unsigned short* __restrict__ WaB,
                  const float* __restrict__ hlin, const float* __restrict__ ba,
                  const float* __restrict__ Wo, float* __restrict__ scores2) {
  __shared__ unsigned short As[2][64 * 64];     // 16 KB
  __shared__ unsigned short Bs[2][256 * 64];    // 64 KB
  const int tid = threadIdx.x;
  const int lane = tid & 63, wn = tid >> 6;     // 4 waves
  // XCD swizzle: 1568 blocks % 8 == 0; N-fastest so the M-pair shares L2.
  const int logical = (blockIdx.x & 7) * 196 + (blockIdx.x >> 3);
  const int m0 = (logical >> 1) * 64;
  const int n0 = (logical & 1) * 256;
  const int g16 = lane >> 4, l16 = lane & 15;
  const int l7 = l16 & 7;
  f32x4 acc[4][4] = {};
  float4 Ra[4], Rb[4];

#define LOADA(REG, KK)                                                                   \
  {                                                                                      \
    _Pragma("unroll")                                                                    \
    for (int it = 0; it < 4; ++it) {                                                     \
      int idx = it * 256 + tid;                                                          \
      int row = idx >> 4, kf = idx & 15;                                                 \
      REG[it] = *reinterpret_cast<const float4*>(att + (size_t)(m0 + row) * F_ + (KK) + kf * 4); \
    }                                                                                    \
  }
#define GLDB(BUF, KK)                                                                    \
  {                                                                                      \
    _Pragma("unroll")                                                                    \
    for (int it = 0; it < 8; ++it) {                                                     \
      int idx = it * 256 + tid;                                                          \
      int row = idx >> 3;                                                                \
      int kc = (idx & 7) ^ (row & 7);                                                    \
      GLOAD_LDS(WaB + (size_t)(n0 + row) * F_ + (KK) + kc * 8, &Bs[BUF][idx * 8]);       \
    }                                                                                    \
  }
#define WRITEA(BUF, REG)                                                                 \
  {                                                                                      \
    _Pragma("unroll")                                                                    \
    for (int it = 0; it < 4; ++it) {                                                     \
      int idx = it * 256 + tid;                                                          \
      int row = idx >> 4, kf = idx & 15;                                                 \
      float4 v = REG[it];                                                                \
      unsigned lo, hi;                                                                   \
      asm("v_cvt_pk_bf16_f32 %0, %1, %2" : "=v"(lo) : "v"(v.x), "v"(v.y));               \
      asm("v_cvt_pk_bf16_f32 %0, %1, %2" : "=v"(hi) : "v"(v.z), "v"(v.w));               \
      uint2 q; q.x = lo; q.y = hi;                                                       \
      int el = row * 64 + (((kf >> 1) ^ (row & 7)) << 3) + ((kf & 1) << 2);              \
      *reinterpret_cast<uint2*>(&As[BUF][el]) = q;                                       \
    }                                                                                    \
  }
#define COMPUTE(BUF)                                                                     \
  {                                                                                      \
    _Pragma("unroll")                                                                    \
    for (int ks = 0; ks < 2; ++ks) {                                                     \
      const int ko = ((ks * 4 + g16) ^ l7) << 3;                                         \
      short8 af[4], bfr[4];                                                              \
      _Pragma("unroll")                                                                  \
      for (int mi = 0; mi < 4; ++mi)                                                     \
        af[mi] = *reinterpret_cast<const short8*>(&As[BUF][(mi * 16 + l16) * 64 + ko]);  \
      _Pragma("unroll")                                                                  \
      for (int ni = 0; ni < 4; ++ni)                                                     \
        bfr[ni] = *reinterpret_cast<const short8*>(&Bs[BUF][(wn * 64 + ni * 16 + l16) * 64 + ko]); \
      _Pragma("unroll")                                                                  \
      for (int mi = 0; mi < 4; ++mi)                                                     \
        _Pragma("unroll")                                                                \
        for (int ni = 0; ni < 4; ++ni)                                                   \
          acc[mi][ni] = __builtin_amdgcn_mfma_f32_16x16x32_bf16(af[mi], bfr[ni], acc[mi][ni], 0, 0, 0); \
    }                                                                                    \
  }

  // prologue: tile0 -> Ra/Bs0 ; tile1 -> Rb/Bs1 (in flight). 12 loads per tile.
  LOADA(Ra, 0);  GLDB(0, 0);
  LOADA(Rb, 64); GLDB(1, 64);
  VMCNT(12);                                          // tile0's 12 done; tile1's 12 in flight
  WRITEA(0, Ra);                                      // As[0] <- tile0
  LGKM0();
  SBAR();

  for (int p = 0; p < 16; ++p) {
    const int t = 2 * p;
    COMPUTE(0);                                       // tile t
    LGKM0();
    SBAR();
    if (t + 2 < 32) {
      LOADA(Ra, (t + 2) * 64); GLDB(0, (t + 2) * 64); // tile t+2 into freed buf0/Ra
      VMCNT(12);                                      // t+1's 12 done; t+2's 12 in flight
    } else {
      VMCNT(0);
    }
    WRITEA(1, Rb);                                    // As[1] <- tile t+1
    LGKM0();
    SBAR();

    COMPUTE(1);                                       // tile t+1
    LGKM0();
    SBAR();
    if (t + 3 < 32) {
      LOADA(Rb, (t + 3) * 64); GLDB(1, (t + 3) * 64); // tile t+3 into freed buf1/Rb
      VMCNT(12);                                      // t+2's 12 done
    } else {
      VMCNT(0);
    }
    if (t + 2 < 32) {
      WRITEA(0, Ra);                                  // As[0] <- tile t+2
    }
    LGKM0();
    SBAR();
  }
#undef LOADA
#undef GLDB
#undef WRITEA
#undef COMPUTE

  // epilogue: per-wave tanh+Wo partial over its 64 cols; cross-wave reduce (red overlays As)
  __syncthreads();
  float* red = (float*)&As[0][0];                     // 4*64 floats
  float wo_v[4], ba_v[4];
  int a_v[4];
  #pragma unroll
  for (int ni = 0; ni < 4; ++ni) {
    int a = n0 + wn * 64 + ni * 16 + l16;
    a_v[ni] = a; wo_v[ni] = Wo[a]; ba_v[ni] = ba[a];
  }
  #pragma unroll
  for (int mi = 0; mi < 4; ++mi) {
    float rs[4];
    #pragma unroll
    for (int j = 0; j < 4; ++j) {
      int m = m0 + mi * 16 + g16 * 4 + j;
      int b = m / L_;
      const float* hb = hlin + (size_t)b * A_;
      float s = 0.f;
      #pragma unroll
      for (int ni = 0; ni < 4; ++ni) {
        float v = acc[mi][ni][j] + ba_v[ni] + hb[a_v[ni]];
        s += fast_tanh(v) * wo_v[ni];
      }
      rs[j] = s;
    }
    #pragma unroll
    for (int off = 1; off < 16; off <<= 1) {
      #pragma unroll
      for (int j = 0; j < 4; ++j) rs[j] += __shfl_xor(rs[j], off);
    }
    if (l16 == 0) {
      #pragma unroll
      for (int j = 0; j < 4; ++j)
        red[wn * 64 + mi * 16 + g16 * 4 + j] = rs[j];
    }
  }
  __syncthreads();
  if (tid < 64) {
    float s = red[tid] + red[64 + tid] + red[128 + tid] + red[192 + tid];
    scores2[(size_t)(m0 + tid) * 2 + (n0 >> 8)] = s;
  }
}

// ---------------- fused softmax + z (f32 att) ----------------
__global__ __launch_bounds__(256)
void z_sm_f32_k(const float* __restrict__ att, const float* __restrict__ scores2,
                unsigned short* __restrict__ AgB) {
  __shared__ float sm[L_];
  const int b = blockIdx.y;
  const int tid = threadIdx.x;
  if (tid < L_) {
    const float* p = scores2 + ((size_t)b * L_ + tid) * 2;
    sm[tid] = p[0] + p[1];
  }
  __syncthreads();
  float mx = -1e30f;
  for (int l = 0; l < L_; ++l) mx = fmaxf(mx, sm[l]);
  float s = 0.f;
  for (int l = 0; l < L_; ++l) s += __expf(sm[l] - mx);
  const float inv = 1.f / s;
  __syncthreads();
  if (tid < L_) sm[tid] = __expf(sm[tid] - mx) * inv;
  __syncthreads();
  const int f0 = blockIdx.x * 1024 + tid * 4;
  const float* base = att + (size_t)b * L_ * F_ + f0;
  float a0 = 0.f, a1 = 0.f, a2 = 0.f, a3 = 0.f;
  #pragma unroll 4
  for (int l = 0; l < L_; ++l) {
    float wl = sm[l];
    float4 a = *reinterpret_cast<const float4*>(base + (size_t)l * F_);
    a0 += wl * a.x; a1 += wl * a.y; a2 += wl * a.z; a3 += wl * a.w;
  }
  ushort4 o;
  o.x = f2bf(a0); o.y = f2bf(a1); o.z = f2bf(a2); o.w = f2bf(a3);
  *reinterpret_cast<ushort4*>(AgB + (size_t)b * 4096 + 2048 + f0) = o;
}

// ---------------- gates GEMM: M=256,N=4096,K=4096. BM=64,BN=64, grid(64,4) ----------------
__global__ __launch_bounds__(256, 4)
void gates_gemm_k(const unsigned short* __restrict__ AgB, const unsigned short* __restrict__ WgB,
                  const float* __restrict__ bi, const float* __restrict__ bh,
                  const float* __restrict__ bz, float* __restrict__ sums) {
  __shared__ unsigned short As[2][64 * 64];
  __shared__ unsigned short Bs[2][64 * 64];
  const int tid = threadIdx.x;
  const int lane = tid & 63, wid = tid >> 6;
  const int wm = wid >> 1, wn = wid & 1;
  const int m0 = blockIdx.y * 64;
  const int n0 = blockIdx.x * 64;
  const int g16 = lane >> 4, l16 = lane & 15;
  const int l7 = l16 & 7;
  f32x4 acc[2][2] = {};

#define STAGE_GG(BUF, KK)                                                               \
  {                                                                                     \
    _Pragma("unroll")                                                                   \
    for (int it = 0; it < 2; ++it) {                                                    \
      int idx = it * 256 + tid;                                                         \
      int row = idx >> 3;                                                               \
      int kc = (idx & 7) ^ (row & 7);                                                   \
      GLOAD_LDS(AgB + (size_t)(m0 + row) * 4096 + (KK) + kc * 8, &As[BUF][idx * 8]);    \
      GLOAD_LDS(WgB + (size_t)(n0 + row) * 4096 + (KK) + kc * 8, &Bs[BUF][idx * 8]);    \
    }                                                                                   \
  }

  STAGE_GG(0, 0);
  STAGE_GG(1, 64);
  VMCNT(4);
  SBAR();
  int cur = 0;
  for (int k0 = 0; k0 < 4096; k0 += 64) {
    #pragma unroll
    for (int ks = 0; ks < 2; ++ks) {
      const int ko = ((ks * 4 + g16) ^ l7) << 3;
      short8 af[2], bfr[2];
      #pragma unroll
      for (int mi = 0; mi < 2; ++mi)
        af[mi] = *reinterpret_cast<const short8*>(&As[cur][(wm * 32 + mi * 16 + l16) * 64 + ko]);
      #pragma unroll
      for (int ni = 0; ni < 2; ++ni)
        bfr[ni] = *reinterpret_cast<const short8*>(&Bs[cur][(wn * 32 + ni * 16 + l16) * 64 + ko]);
      #pragma unroll
      for (int mi = 0; mi < 2; ++mi)
        #pragma unroll
        for (int ni = 0; ni < 2; ++ni)
          acc[mi][ni] = __builtin_amdgcn_mfma_f32_16x16x32_bf16(af[mi], bfr[ni], acc[mi][ni], 0, 0, 0);
    }
    LGKM0();
    SBAR();
    if (k0 + 128 < 4096) {
      STAGE_GG(cur, k0 + 128);
      VMCNT(4);
    } else {
      VMCNT(0);
    }
    SBAR();
    cur ^= 1;
  }
#undef STAGE_GG

  #pragma unroll
  for (int ni = 0; ni < 2; ++ni) {
    int col = n0 + wn * 32 + ni * 16 + l16;
    float bsum = bi[col] + bh[col] + bz[col];
    #pragma unroll
    for (int mi = 0; mi < 2; ++mi)
      #pragma unroll
      for (int j = 0; j < 4; ++j) {
        int m = m0 + wm * 32 + mi * 16 + g16 * 4 + j;
        sums[(size_t)m * 4096 + col] = acc[mi][ni][j] + bsum;
      }
  }
}

// ---------------- gates + zoneout elementwise ----------------
__global__ void final_k(const float* __restrict__ sums, const float* __restrict__ h,
                        const float* __restrict__ c, float* __restrict__ out) {
  int i = blockIdx.x * 256 + threadIdx.x;   // 0 .. B_*H_-1
  int b = i >> 10, hh = i & 1023;
  const float* srow = sums + (size_t)b * 4096;
  float ig = sigmoidf_(srow[hh]);
  float fg = sigmoidf_(srow[1024 + hh]);
  float og = sigmoidf_(srow[2048 + hh]);
  float g  = fast_tanh(srow[3072 + hh]);
  float cv = c[i], hv = h[i];
  float nc = 0.5f * cv + 0.5f * (fg * cv + ig * g);
  float nh = 0.5f * hv + 0.5f * (og * fast_tanh(nc));
  out[i] = nh;
  out[B_ * H_ + i] = nh;
  out[2 * B_ * H_ + i] = nc;
}

extern "C" void kernel_launch(void* const* d_in, const int* in_sizes, int n_in,
                              void* d_out, int out_size, void* d_ws, size_t ws_size,
                              hipStream_t stream) {
  const float* xt  = (const float*)d_in[0];
  const float* att = (const float*)d_in[1];
  const float* h   = (const float*)d_in[2];
  const float* c   = (const float*)d_in[3];
  const float* Wi  = (const float*)d_in[4];
  const float* bi  = (const float*)d_in[5];
  const float* Wh  = (const float*)d_in[6];
  const float* bh  = (const float*)d_in[7];
  const float* Wz  = (const float*)d_in[8];
  const float* bz  = (const float*)d_in[9];
  const float* Wa  = (const float*)d_in[10];
  const float* ba  = (const float*)d_in[11];
  const float* Wha = (const float*)d_in[12];
  const float* bha = (const float*)d_in[13];
  const float* Wo  = (const float*)d_in[14];
  // bo (d_in[15]) is a constant shift under softmax -> dropped.

  char* ws = (char*)d_ws;
  const size_t MB = (size_t)1 << 20;
  unsigned short* WaB  = (unsigned short*)(ws);                // 2 MB
  unsigned short* WhaB = (unsigned short*)(ws + 2 * MB);       // 1 MB
  unsigned short* WgB  = (unsigned short*)(ws + 3 * MB);       // 32 MB
  unsigned short* AgB  = (unsigned short*)(ws + 35 * MB);      // 2 MB
  float* hlin    = (float*)(ws + 37 * MB);                     // 0.5 MB
  float* scores2 = (float*)(ws + 38 * MB);                     // 0.4 MB
  float* sums    = (float*)(ws + 40 * MB);                     // 4 MB
  float* out = (float*)d_out;

  cast_wx_k<<<9216, 256, 0, stream>>>(Wa, Wha, Wi, Wh, Wz, xt, h, WaB, WhaB, WgB, AgB);
  hlin_gemm_k<<<dim3(4, 4), 256, 0, stream>>>(AgB, WhaB, bha, hlin);
  score_fuse_k<<<(ML / 64) * 2, 256, 0, stream>>>(att, WaB, hlin, ba, Wo, scores2);
  z_sm_f32_k<<<dim3(2, B_), 256, 0, stream>>>(att, scores2, AgB);
  gates_gemm_k<<<dim3(64, 4), 256, 0, stream>>>(AgB, WgB, bi, bh, bz, sums);
  final_k<<<B_ * H_ / 256, 256, 0, stream>>>(sums, h, c, out);
}